// Round 12
// baseline (1459.116 us; speedup 1.0000x reference)
//
#include <hip/hip_runtime.h>
#include <math.h>

#define N_NODES 100000
#define N_PAD   100032          // 1563 * 64
#define N_EDGES 1600000
#define F_IN    92
#define H_DIM   128
#define STEPS   6
#define G_GRAPHS 256
#define TH3     384
#define SSTR    136             // LDS tile row stride (ushorts): 272B = 17*16B, b128-aligned
#define HSTR    132             // LDS hn-tile row stride (floats): 2-way bank alias max
#define FPASS   8               // fill locality passes
#define FRANGE  12500           // nodes per pass (8*12500 = 100000 exact)

typedef __attribute__((ext_vector_type(8))) short bf16x8;
typedef __attribute__((ext_vector_type(4))) float f32x4;

__device__ __forceinline__ unsigned short f2bf(float x) {   // fp32 -> bf16 RNE
    unsigned u = __float_as_uint(x);
    return (unsigned short)((u + 0x7fffu + ((u >> 16) & 1u)) >> 16);
}
__device__ __forceinline__ float bf2f(unsigned short h) {
    return __uint_as_float(((unsigned)h) << 16);
}

// ---------------- precompute: M2[i][j][k] = sum_c Wm[i][k][c] * w_ih[j][c] (col-major) ----
__global__ void fuse_w_kernel(const float* __restrict__ Wm, const float* __restrict__ w_ih,
                              float* __restrict__ M2) {
    int ij = blockIdx.x;            // STEPS*384 = 2304 blocks
    int i  = ij / TH3;
    int j  = ij - i * TH3;
    int k  = threadIdx.x;           // 128 threads
    __shared__ float wj[H_DIM];
    wj[k] = w_ih[j * H_DIM + k];
    __syncthreads();
    const float* wr = Wm + ((size_t)i * H_DIM + k) * H_DIM;
    float acc = 0.f;
    #pragma unroll 4
    for (int c = 0; c < H_DIM; ++c) acc = fmaf(wj[c], wr[c], acc);
    M2[((size_t)i * TH3 + j) * H_DIM + k] = acc;
}

// ---------------- pack weights into MFMA B-fragment order, split hi/lo bf16 ----------------
// fragIdx b = mg*32 + ct*4 + kc (mg = mat*3+g); element: B[k=kc*32+(lane>>4)*8+jj][j=g*128+ct*16+(lane&15)]
// mat 0..5 -> fused M step mats; mat 6 -> w_hh ([384][128] native col-major)
__global__ void pack_kernel(const float* __restrict__ M6, const float* __restrict__ w_hh,
                            unsigned short* __restrict__ PBhi, unsigned short* __restrict__ PBlo) {
    int b    = blockIdx.x;          // 672 = 21*32
    int lane = threadIdx.x;         // 64
    int kc   = b & 3;
    int ct   = (b >> 2) & 7;
    int mg   = b >> 5;              // 0..20
    int g    = mg % 3;
    int mat  = mg / 3;
    int j    = g * 128 + ct * 16 + (lane & 15);
    int k0   = kc * 32 + (lane >> 4) * 8;
    size_t outBase = ((size_t)b * 64 + lane) * 8;
    #pragma unroll
    for (int jj = 0; jj < 8; ++jj) {
        int k = k0 + jj;
        float v = (mat < 6) ? M6[((size_t)mat * TH3 + j) * H_DIM + k]
                            : w_hh[(size_t)j * H_DIM + k];
        unsigned short hv = f2bf(v);
        PBhi[outBase + jj] = hv;
        PBlo[outBase + jj] = f2bf(v - bf2f(hv));
    }
}

// ---------------- embed: h = tanh(x @ W_embed), output split bf16 hi/lo ----------------
#define ET 16
__global__ void embed_kernel(const float* __restrict__ x, const float* __restrict__ We,
                             unsigned short* __restrict__ h_hi, unsigned short* __restrict__ h_lo) {
    int n0 = blockIdx.x * ET;       // 6250 blocks, exact
    int j  = threadIdx.x;           // 128 threads
    __shared__ float xs[ET * F_IN];
    for (int i = j; i < ET * F_IN; i += H_DIM) xs[i] = x[n0 * F_IN + i];
    __syncthreads();
    float acc[ET];
    #pragma unroll
    for (int n = 0; n < ET; ++n) acc[n] = 0.f;
    const float4* xs4 = (const float4*)xs;
    for (int k4 = 0; k4 < F_IN / 4; ++k4) {
        int k = k4 * 4;
        float w0 = We[(k + 0) * H_DIM + j];
        float w1 = We[(k + 1) * H_DIM + j];
        float w2 = We[(k + 2) * H_DIM + j];
        float w3 = We[(k + 3) * H_DIM + j];
        #pragma unroll
        for (int n = 0; n < ET; ++n) {
            float4 a = xs4[n * (F_IN / 4) + k4];
            acc[n] = fmaf(a.x, w0, acc[n]);
            acc[n] = fmaf(a.y, w1, acc[n]);
            acc[n] = fmaf(a.z, w2, acc[n]);
            acc[n] = fmaf(a.w, w3, acc[n]);
        }
    }
    #pragma unroll
    for (int n = 0; n < ET; ++n) {
        float e2 = __expf(2.f * acc[n]);
        float v  = 1.f - 2.f / (e2 + 1.f);
        size_t o = (size_t)(n0 + n) * H_DIM + j;
        unsigned short hv = f2bf(v);
        h_hi[o] = hv;
        h_lo[o] = f2bf(v - bf2f(hv));
    }
}

// ---------------- CSR build: histogram -> scan -> bucket fill ----------------
__global__ void hist_kernel(const int* __restrict__ dst, int* __restrict__ count) {
    int e = blockIdx.x * 256 + threadIdx.x;
    if (e < N_EDGES) atomicAdd(&count[dst[e]], 1);
}

__global__ void scan_block_kernel(const int* __restrict__ count, int* __restrict__ offs,
                                  int* __restrict__ blockSums) {
    __shared__ int tmp[256];
    int i = blockIdx.x * 256 + threadIdx.x;
    int t = threadIdx.x;
    int v = (i < N_NODES) ? count[i] : 0;
    tmp[t] = v;
    __syncthreads();
    for (int d = 1; d < 256; d <<= 1) {
        int add = (t >= d) ? tmp[t - d] : 0;
        __syncthreads();
        tmp[t] += add;
        __syncthreads();
    }
    if (i < N_NODES) offs[i] = tmp[t] - v;
    if (t == 255) blockSums[blockIdx.x] = tmp[255];
}

__global__ void scan_sums_kernel(int* __restrict__ blockSums, int nb) {  // 1 block, 512 thr
    __shared__ int tmp[512];
    int t = threadIdx.x;
    int v = (t < nb) ? blockSums[t] : 0;
    tmp[t] = v;
    __syncthreads();
    for (int d = 1; d < 512; d <<= 1) {
        int add = (t >= d) ? tmp[t - d] : 0;
        __syncthreads();
        tmp[t] += add;
        __syncthreads();
    }
    if (t < nb) blockSums[t] = tmp[t] - v;
}

__global__ void scan_add_kernel(int* __restrict__ offs, const int* __restrict__ blockSums) {
    int i = blockIdx.x * 256 + threadIdx.x;
    if (i < N_NODES) offs[i] += blockSums[blockIdx.x];
    if (i == 0) offs[N_NODES] = N_EDGES;
}

// fill with temporal-locality passes (writes confined to ~0.8 MB L2-resident slices)
__global__ void fill_kernel(const int* __restrict__ src, const int* __restrict__ dst,
                            const int* __restrict__ offs, int* __restrict__ cursor,
                            int* __restrict__ srcSorted) {
    int e = blockIdx.x * 256 + threadIdx.x;
    if (e >= N_EDGES) return;
    for (int p = 0; p < FPASS; ++p) {
        int lo = p * FRANGE;
        int d = dst[e];
        if (d >= lo && d < lo + FRANGE) {
            int pos = atomicAdd(&cursor[d], 1);
            srcSorted[offs[d] + pos] = src[e];
        }
    }
}

// ---------------- gather: s[n] = sum of h_hi[src] rows, bf16 output ----------------
__global__ void gather_kernel(const unsigned short* __restrict__ h_hi,
                              const int* __restrict__ offs, const int* __restrict__ srcS,
                              unsigned short* __restrict__ sv) {
    int tid  = blockIdx.x * 256 + threadIdx.x;   // N_PAD*16 threads, 6252 blocks exact
    int node = tid >> 4;
    int c8   = (tid & 15) * 8;
    float a[8];
    #pragma unroll
    for (int j = 0; j < 8; ++j) a[j] = 0.f;
    if (node < N_NODES) {
        int beg = offs[node], end = offs[node + 1];
        int i = beg;
        for (; i + 4 <= end; i += 4) {
            int n0 = srcS[i], n1 = srcS[i + 1], n2 = srcS[i + 2], n3 = srcS[i + 3];
            bf16x8 v0 = *(const bf16x8*)(h_hi + (size_t)n0 * H_DIM + c8);
            bf16x8 v1 = *(const bf16x8*)(h_hi + (size_t)n1 * H_DIM + c8);
            bf16x8 v2 = *(const bf16x8*)(h_hi + (size_t)n2 * H_DIM + c8);
            bf16x8 v3 = *(const bf16x8*)(h_hi + (size_t)n3 * H_DIM + c8);
            #pragma unroll
            for (int j = 0; j < 8; ++j)
                a[j] += (bf2f((unsigned short)v0[j]) + bf2f((unsigned short)v1[j]))
                      + (bf2f((unsigned short)v2[j]) + bf2f((unsigned short)v3[j]));
        }
        if (i + 2 <= end) {
            int n0 = srcS[i], n1 = srcS[i + 1];
            bf16x8 v0 = *(const bf16x8*)(h_hi + (size_t)n0 * H_DIM + c8);
            bf16x8 v1 = *(const bf16x8*)(h_hi + (size_t)n1 * H_DIM + c8);
            #pragma unroll
            for (int j = 0; j < 8; ++j)
                a[j] += bf2f((unsigned short)v0[j]) + bf2f((unsigned short)v1[j]);
            i += 2;
        }
        if (i < end) {
            int n0 = srcS[i];
            bf16x8 v0 = *(const bf16x8*)(h_hi + (size_t)n0 * H_DIM + c8);
            #pragma unroll
            for (int j = 0; j < 8; ++j) a[j] += bf2f((unsigned short)v0[j]);
        }
    }
    bf16x8 o;
    #pragma unroll
    for (int j = 0; j < 8; ++j) o[j] = (short)f2bf(a[j]);
    *(bf16x8*)(sv + (size_t)node * H_DIM + c8) = o;   // node < N_PAD always
}

// ---------------- GRU step via MFMA ----------------
// Block = 8 waves = 64 rows x 128 ch; wave ct owns 64 rows x 16 ch.
// Accumulator merge: r,z gates chain BOTH GEMMs (s@M and h@w_hh) into one C-tile each;
// only the n-gate keeps i_n/h_n separate -> 4 C-sets = 64 acc regs (was 96), so
// launch_bounds(512,4) fits 4 waves/SIMD (2 blocks/CU) vs 2 before.
// s A-frags read direct from global (dense 64B lines, L1-shared across waves);
// h staged in LDS (needed for hold). LDS 34.8 KB. In-place h is race-free per block.
__global__ __launch_bounds__(512, 4) void gru_kernel(
    const unsigned short* __restrict__ sv,
    unsigned short* __restrict__ h_hi, unsigned short* __restrict__ h_lo,
    const unsigned short* __restrict__ PBhi, const unsigned short* __restrict__ PBlo,
    int matI, const float* __restrict__ b_ih, const float* __restrict__ b_hh)
{
    __shared__ __align__(16) unsigned short buf[2 * 64 * SSTR];   // 34.8 KB
    unsigned short* sHh = buf;                  // h_hi tile
    unsigned short* sHl = buf + 64 * SSTR;      // h_lo tile
    float* hnF = (float*)buf;                   // epilogue reuse: 64*HSTR fp32 (33.8 KB)

    int nt = blockIdx.x;            // 1563
    int rowBase = nt * 64;
    int t = threadIdx.x;            // 512

    // phase 0: stage h tiles. 64 rows x 16 chunks of 8 ushorts; 512 threads x 2 chunks.
    #pragma unroll
    for (int i = t; i < 64 * 16; i += 512) {
        int row = i >> 4;
        int c8  = (i & 15) * 8;
        size_t g = (size_t)(rowBase + row) * H_DIM + c8;
        int l = row * SSTR + c8;
        *(bf16x8*)&sHh[l] = *(const bf16x8*)(h_hi + g);
        *(bf16x8*)&sHl[l] = *(const bf16x8*)(h_lo + g);
    }
    __syncthreads();

    int lane = t & 63;
    int ct   = t >> 6;              // wave id = channel tile 0..7
    int rloc = lane & 15;
    int kOff = (lane >> 4) * 8;

    f32x4 accRZ[2][4], accIn[4], accHn[4];   // merged r,z; split n
    #pragma unroll
    for (int rs = 0; rs < 4; ++rs) {
        accRZ[0][rs] = (f32x4){0.f, 0.f, 0.f, 0.f};
        accRZ[1][rs] = (f32x4){0.f, 0.f, 0.f, 0.f};
        accIn[rs]    = (f32x4){0.f, 0.f, 0.f, 0.f};
        accHn[rs]    = (f32x4){0.f, 0.f, 0.f, 0.f};
    }

    const int fI0 = matI * 3;
    for (int kc = 0; kc < 4; ++kc) {
        int aOff = kc * 32 + kOff;
        // s A-frags: direct global, dense 64B lines (L1-shared across the 8 waves)
        bf16x8 aS[4];
        #pragma unroll
        for (int rs = 0; rs < 4; ++rs)
            aS[rs] = *(const bf16x8*)(sv + (size_t)(rowBase + rs * 16 + rloc) * H_DIM + aOff);
        // h A-frags from LDS
        bf16x8 aHh4[4], aHl4[4];
        #pragma unroll
        for (int rs = 0; rs < 4; ++rs) {
            int al = (rs * 16 + rloc) * SSTR + aOff;
            aHh4[rs] = *(const bf16x8*)(&sHh[al]);
            aHl4[rs] = *(const bf16x8*)(&sHl[al]);
        }
        #pragma unroll
        for (int g = 0; g < 3; ++g) {
            size_t oI = ((size_t)((fI0 + g) * 32 + ct * 4 + kc) * 64 + lane) * 8;
            size_t oH = ((size_t)((18  + g) * 32 + ct * 4 + kc) * 64 + lane) * 8;
            bf16x8 bIh = *(const bf16x8*)(PBhi + oI);
            bf16x8 bIl = *(const bf16x8*)(PBlo + oI);
            bf16x8 bHh = *(const bf16x8*)(PBhi + oH);
            bf16x8 bHl = *(const bf16x8*)(PBlo + oH);
            #pragma unroll
            for (int rs = 0; rs < 4; ++rs) {
                f32x4* tI = (g == 0) ? &accRZ[0][rs] : (g == 1) ? &accRZ[1][rs] : &accIn[rs];
                f32x4* tH = (g == 2) ? &accHn[rs] : tI;
                *tI = __builtin_amdgcn_mfma_f32_16x16x32_bf16(aS[rs],   bIh, *tI, 0, 0, 0);
                *tI = __builtin_amdgcn_mfma_f32_16x16x32_bf16(aS[rs],   bIl, *tI, 0, 0, 0);
                *tH = __builtin_amdgcn_mfma_f32_16x16x32_bf16(aHh4[rs], bHh, *tH, 0, 0, 0);
                *tH = __builtin_amdgcn_mfma_f32_16x16x32_bf16(aHl4[rs], bHh, *tH, 0, 0, 0);
                *tH = __builtin_amdgcn_mfma_f32_16x16x32_bf16(aHh4[rs], bHl, *tH, 0, 0, 0);
            }
        }
    }

    // ---- epilogue: thread-local GRU for all 16 values, then single LDS round-trip ----
    int c = ct * 16 + rloc;
    float br  = b_ih[c] + b_hh[c];               // merged r bias
    float bz  = b_ih[128 + c] + b_hh[128 + c];   // merged z bias
    float bin = b_ih[256 + c], bhn = b_hh[256 + c];
    int rl = (lane >> 4) * 4;       // local row base within each 16-row subtile

    float hnv[4][4];
    #pragma unroll
    for (int rs = 0; rs < 4; ++rs) {
        #pragma unroll
        for (int r = 0; r < 4; ++r) {
            int lrow = rs * 16 + rl + r;
            float hold = bf2f(sHh[lrow * SSTR + c]) + bf2f(sHl[lrow * SSTR + c]);
            float rr = 1.f / (1.f + __expf(-(accRZ[0][rs][r] + br)));
            float zz = 1.f / (1.f + __expf(-(accRZ[1][rs][r] + bz)));
            float pre = (accIn[rs][r] + bin) + rr * (accHn[rs][r] + bhn);
            float e2 = __expf(2.f * pre);
            float cand = 1.f - 2.f / (e2 + 1.f);  // tanh, overflow-safe
            hnv[rs][r] = (1.f - zz) * cand + zz * hold;
        }
    }
    __syncthreads();                // all hold reads done; tiles now reusable
    #pragma unroll
    for (int rs = 0; rs < 4; ++rs)
        #pragma unroll
        for (int r = 0; r < 4; ++r)
            hnF[(rs * 16 + rl + r) * HSTR + c] = hnv[rs][r];   // 2-way bank alias: free
    __syncthreads();                // hn tile complete
    // coop store: 64 rows x 32 float4 chunks = 2048, 512 threads x 4
    #pragma unroll
    for (int i = t; i < 64 * 32; i += 512) {
        int row = i >> 5;
        int c4  = (i & 31) * 4;
        int gRow = rowBase + row;
        if (gRow < N_NODES) {
            float4 v = *(const float4*)(&hnF[row * HSTR + c4]);
            ushort4 hh, ll;
            hh.x = f2bf(v.x); ll.x = f2bf(v.x - bf2f(hh.x));
            hh.y = f2bf(v.y); ll.y = f2bf(v.y - bf2f(hh.y));
            hh.z = f2bf(v.z); ll.z = f2bf(v.z - bf2f(hh.z));
            hh.w = f2bf(v.w); ll.w = f2bf(v.w - bf2f(hh.w));
            size_t o = (size_t)gRow * H_DIM + c4;
            *(ushort4*)(h_hi + o) = hh;
            *(ushort4*)(h_lo + o) = ll;
        }
    }
}

// ---------------- pool phase A: per-block segment partial sums + atomicAdd ----------------
__global__ void pool_partial(const unsigned short* __restrict__ h_hi,
                             const unsigned short* __restrict__ h_lo,
                             const int* __restrict__ batch,
                             float* __restrict__ pooled) {
    int b = blockIdx.x;             // 1563
    int t = threadIdx.x;            // 128
    int n0 = b * 64;
    if (n0 >= N_NODES) return;
    int nEnd = n0 + 64 < N_NODES ? n0 + 64 : N_NODES;
    int curG = batch[n0];
    float acc = 0.f;
    for (int n = n0; n < nEnd; ++n) {
        int g = batch[n];           // uniform across block
        if (g != curG) {            // uniform branch
            atomicAdd(&pooled[curG * H_DIM + t], acc);
            acc = 0.f;
            curG = g;
        }
        size_t o = (size_t)n * H_DIM + t;
        acc += bf2f(h_hi[o]) + bf2f(h_lo[o]);
    }
    atomicAdd(&pooled[curG * H_DIM + t], acc);
}

// ---------------- pool phase B: normalize + relu + prediction head ----------------
__global__ void pool_head(const float* __restrict__ pooled, const int* __restrict__ batch,
                          const float* __restrict__ w_pred, const float* __restrict__ b_pred,
                          float* __restrict__ out) {
    int g = blockIdx.x;             // 256 blocks
    int t = threadIdx.x;            // 128 threads
    __shared__ int bounds[2];
    __shared__ float red[2];
    if (t < 2) {
        int target = g + t;
        int lo = 0, hi = N_NODES;
        while (lo < hi) {
            int mid = (lo + hi) >> 1;
            if (batch[mid] < target) lo = mid + 1; else hi = mid;
        }
        bounds[t] = lo;
    }
    __syncthreads();
    int cnt = bounds[1] - bounds[0];
    float pv = pooled[g * H_DIM + t] / fmaxf((float)cnt, 1.f);
    pv = fmaxf(pv, 0.f);
    float v = pv * w_pred[t];
    #pragma unroll
    for (int off = 32; off > 0; off >>= 1) v += __shfl_down(v, off);
    if ((t & 63) == 0) red[t >> 6] = v;
    __syncthreads();
    if (t == 0) out[g] = red[0] + red[1] + b_pred[0];
}

extern "C" void kernel_launch(void* const* d_in, const int* in_sizes, int n_in,
                              void* d_out, int out_size, void* d_ws, size_t ws_size,
                              hipStream_t stream) {
    const float* x      = (const float*)d_in[0];
    const int*   ei     = (const int*)d_in[1];    // [2,E]: src = ei, dst = ei+E
    const int*   batch  = (const int*)d_in[2];
    const float* We     = (const float*)d_in[3];
    const float* Wm     = (const float*)d_in[4];
    const float* w_ih   = (const float*)d_in[5];
    const float* w_hh   = (const float*)d_in[6];  // [384][128] native col-major
    const float* b_ih   = (const float*)d_in[7];
    const float* b_hh   = (const float*)d_in[8];
    const float* w_pred = (const float*)d_in[9];
    const float* b_pred = (const float*)d_in[10];
    float* out = (float*)d_out;

    const size_t HN = (size_t)N_PAD * H_DIM;
    unsigned short* h_hi = (unsigned short*)d_ws;
    unsigned short* h_lo = h_hi + HN;
    unsigned short* sv   = h_lo + HN;                              // s, bf16 only
    float* M6 = (float*)(sv + HN);                                 // 6*384*128 fp32
    unsigned short* PBhi = (unsigned short*)(M6 + (size_t)STEPS * TH3 * H_DIM);
    unsigned short* PBlo = PBhi + 21 * 32 * 64 * 8;
    int* offs      = (int*)(PBlo + 21 * 32 * 64 * 8);              // N+1
    int* srcSorted = offs + (N_NODES + 1);                         // E
    float* pooled  = (float*)(srcSorted + N_EDGES);                // 256*128 fp32
    // CSR temporaries overlaid on sv (sv first written by gather, after CSR build)
    int* count     = (int*)sv;
    int* cursor    = count + N_NODES;
    int* blockSums = cursor + N_NODES;

    const int* esrc = ei;
    const int* edst = ei + N_EDGES;
    const int EB = (N_EDGES + 255) / 256;                // 6250
    const int NB = (N_NODES + 255) / 256;                // 391

    hipMemsetAsync(count, 0, 2 * (size_t)N_NODES * sizeof(int), stream);
    hipMemsetAsync(pooled, 0, (size_t)G_GRAPHS * H_DIM * sizeof(float), stream);
    hist_kernel<<<EB, 256, 0, stream>>>(edst, count);
    scan_block_kernel<<<NB, 256, 0, stream>>>(count, offs, blockSums);
    scan_sums_kernel<<<1, 512, 0, stream>>>(blockSums, NB);
    scan_add_kernel<<<NB, 256, 0, stream>>>(offs, blockSums);
    fill_kernel<<<EB, 256, 0, stream>>>(esrc, edst, offs, cursor, srcSorted);

    fuse_w_kernel<<<STEPS * TH3, H_DIM, 0, stream>>>(Wm, w_ih, M6);
    pack_kernel<<<21 * 32, 64, 0, stream>>>(M6, w_hh, PBhi, PBlo);
    embed_kernel<<<N_NODES / ET, H_DIM, 0, stream>>>(x, We, h_hi, h_lo);

    for (int i = 0; i < STEPS; ++i) {
        gather_kernel<<<(N_PAD * 16) / 256, 256, 0, stream>>>(h_hi, offs, srcSorted, sv);
        gru_kernel<<<N_PAD / 64, 512, 0, stream>>>(sv, h_hi, h_lo, PBhi, PBlo,
                                                   i, b_ih, b_hh);
    }

    pool_partial<<<N_PAD / 64, H_DIM, 0, stream>>>(h_hi, h_lo, batch, pooled);
    pool_head<<<G_GRAPHS, H_DIM, 0, stream>>>(pooled, batch, w_pred, b_pred, out);
}

// Round 13
// 1184.808 us; speedup vs baseline: 1.2315x; 1.2315x over previous
//
#include <hip/hip_runtime.h>
#include <math.h>

#define N_NODES 100000
#define N_PAD   100032          // 3126 * 32
#define N_EDGES 1600000
#define F_IN    92
#define H_DIM   128
#define STEPS   6
#define G_GRAPHS 256
#define TH3     384
#define SSTR    136             // LDS tile row stride (ushorts): 272B = 17*16B, b128-aligned
#define HSTR    132             // LDS hn-tile row stride (floats): 2-way bank alias max
#define FPASS   8               // fill locality passes
#define FRANGE  12500           // nodes per pass (8*12500 = 100000 exact)

typedef __attribute__((ext_vector_type(8))) short bf16x8;
typedef __attribute__((ext_vector_type(4))) float f32x4;

__device__ __forceinline__ unsigned short f2bf(float x) {   // fp32 -> bf16 RNE
    unsigned u = __float_as_uint(x);
    return (unsigned short)((u + 0x7fffu + ((u >> 16) & 1u)) >> 16);
}
__device__ __forceinline__ float bf2f(unsigned short h) {
    return __uint_as_float(((unsigned)h) << 16);
}

// ---------------- precompute: M2[i][j][k] = sum_c Wm[i][k][c] * w_ih[j][c] (col-major) ----
__global__ void fuse_w_kernel(const float* __restrict__ Wm, const float* __restrict__ w_ih,
                              float* __restrict__ M2) {
    int ij = blockIdx.x;            // STEPS*384 = 2304 blocks
    int i  = ij / TH3;
    int j  = ij - i * TH3;
    int k  = threadIdx.x;           // 128 threads
    __shared__ float wj[H_DIM];
    wj[k] = w_ih[j * H_DIM + k];
    __syncthreads();
    const float* wr = Wm + ((size_t)i * H_DIM + k) * H_DIM;
    float acc = 0.f;
    #pragma unroll 4
    for (int c = 0; c < H_DIM; ++c) acc = fmaf(wj[c], wr[c], acc);
    M2[((size_t)i * TH3 + j) * H_DIM + k] = acc;
}

// ---------------- pack weights into MFMA B-fragment order, split hi/lo bf16 ----------------
// fragIdx b = mg*32 + ct*4 + kc (mg = mat*3+g); element: B[k=kc*32+(lane>>4)*8+jj][j=g*128+ct*16+(lane&15)]
// mat 0..5 -> fused M step mats; mat 6 -> w_hh ([384][128] native col-major)
__global__ void pack_kernel(const float* __restrict__ M6, const float* __restrict__ w_hh,
                            unsigned short* __restrict__ PBhi, unsigned short* __restrict__ PBlo) {
    int b    = blockIdx.x;          // 672 = 21*32
    int lane = threadIdx.x;         // 64
    int kc   = b & 3;
    int ct   = (b >> 2) & 7;
    int mg   = b >> 5;              // 0..20
    int g    = mg % 3;
    int mat  = mg / 3;
    int j    = g * 128 + ct * 16 + (lane & 15);
    int k0   = kc * 32 + (lane >> 4) * 8;
    size_t outBase = ((size_t)b * 64 + lane) * 8;
    #pragma unroll
    for (int jj = 0; jj < 8; ++jj) {
        int k = k0 + jj;
        float v = (mat < 6) ? M6[((size_t)mat * TH3 + j) * H_DIM + k]
                            : w_hh[(size_t)j * H_DIM + k];
        unsigned short hv = f2bf(v);
        PBhi[outBase + jj] = hv;
        PBlo[outBase + jj] = f2bf(v - bf2f(hv));
    }
}

// ---------------- embed: h = tanh(x @ W_embed), output split bf16 hi/lo ----------------
#define ET 16
__global__ void embed_kernel(const float* __restrict__ x, const float* __restrict__ We,
                             unsigned short* __restrict__ h_hi, unsigned short* __restrict__ h_lo) {
    int n0 = blockIdx.x * ET;       // 6250 blocks, exact
    int j  = threadIdx.x;           // 128 threads
    __shared__ float xs[ET * F_IN];
    for (int i = j; i < ET * F_IN; i += H_DIM) xs[i] = x[n0 * F_IN + i];
    __syncthreads();
    float acc[ET];
    #pragma unroll
    for (int n = 0; n < ET; ++n) acc[n] = 0.f;
    const float4* xs4 = (const float4*)xs;
    for (int k4 = 0; k4 < F_IN / 4; ++k4) {
        int k = k4 * 4;
        float w0 = We[(k + 0) * H_DIM + j];
        float w1 = We[(k + 1) * H_DIM + j];
        float w2 = We[(k + 2) * H_DIM + j];
        float w3 = We[(k + 3) * H_DIM + j];
        #pragma unroll
        for (int n = 0; n < ET; ++n) {
            float4 a = xs4[n * (F_IN / 4) + k4];
            acc[n] = fmaf(a.x, w0, acc[n]);
            acc[n] = fmaf(a.y, w1, acc[n]);
            acc[n] = fmaf(a.z, w2, acc[n]);
            acc[n] = fmaf(a.w, w3, acc[n]);
        }
    }
    #pragma unroll
    for (int n = 0; n < ET; ++n) {
        float e2 = __expf(2.f * acc[n]);
        float v  = 1.f - 2.f / (e2 + 1.f);
        size_t o = (size_t)(n0 + n) * H_DIM + j;
        unsigned short hv = f2bf(v);
        h_hi[o] = hv;
        h_lo[o] = f2bf(v - bf2f(hv));
    }
}

// ---------------- CSR build: histogram -> scan -> bucket fill ----------------
__global__ void hist_kernel(const int* __restrict__ dst, int* __restrict__ count) {
    int e = blockIdx.x * 256 + threadIdx.x;
    if (e < N_EDGES) atomicAdd(&count[dst[e]], 1);
}

__global__ void scan_block_kernel(const int* __restrict__ count, int* __restrict__ offs,
                                  int* __restrict__ blockSums) {
    __shared__ int tmp[256];
    int i = blockIdx.x * 256 + threadIdx.x;
    int t = threadIdx.x;
    int v = (i < N_NODES) ? count[i] : 0;
    tmp[t] = v;
    __syncthreads();
    for (int d = 1; d < 256; d <<= 1) {
        int add = (t >= d) ? tmp[t - d] : 0;
        __syncthreads();
        tmp[t] += add;
        __syncthreads();
    }
    if (i < N_NODES) offs[i] = tmp[t] - v;
    if (t == 255) blockSums[blockIdx.x] = tmp[255];
}

__global__ void scan_sums_kernel(int* __restrict__ blockSums, int nb) {  // 1 block, 512 thr
    __shared__ int tmp[512];
    int t = threadIdx.x;
    int v = (t < nb) ? blockSums[t] : 0;
    tmp[t] = v;
    __syncthreads();
    for (int d = 1; d < 512; d <<= 1) {
        int add = (t >= d) ? tmp[t - d] : 0;
        __syncthreads();
        tmp[t] += add;
        __syncthreads();
    }
    if (t < nb) blockSums[t] = tmp[t] - v;
}

__global__ void scan_add_kernel(int* __restrict__ offs, const int* __restrict__ blockSums) {
    int i = blockIdx.x * 256 + threadIdx.x;
    if (i < N_NODES) offs[i] += blockSums[blockIdx.x];
    if (i == 0) offs[N_NODES] = N_EDGES;
}

// fill with temporal-locality passes (writes confined to ~0.8 MB L2-resident slices)
__global__ void fill_kernel(const int* __restrict__ src, const int* __restrict__ dst,
                            const int* __restrict__ offs, int* __restrict__ cursor,
                            int* __restrict__ srcSorted) {
    int e = blockIdx.x * 256 + threadIdx.x;
    if (e >= N_EDGES) return;
    for (int p = 0; p < FPASS; ++p) {
        int lo = p * FRANGE;
        int d = dst[e];
        if (d >= lo && d < lo + FRANGE) {
            int pos = atomicAdd(&cursor[d], 1);
            srcSorted[offs[d] + pos] = src[e];
        }
    }
}

// ---------------- gather: s[n] = sum of h_hi[src] rows, bf16 output ----------------
__global__ void gather_kernel(const unsigned short* __restrict__ h_hi,
                              const int* __restrict__ offs, const int* __restrict__ srcS,
                              unsigned short* __restrict__ sv) {
    int tid  = blockIdx.x * 256 + threadIdx.x;   // N_PAD*16 threads, 6252 blocks exact
    int node = tid >> 4;
    int c8   = (tid & 15) * 8;
    float a[8];
    #pragma unroll
    for (int j = 0; j < 8; ++j) a[j] = 0.f;
    if (node < N_NODES) {
        int beg = offs[node], end = offs[node + 1];
        int i = beg;
        for (; i + 4 <= end; i += 4) {
            int n0 = srcS[i], n1 = srcS[i + 1], n2 = srcS[i + 2], n3 = srcS[i + 3];
            bf16x8 v0 = *(const bf16x8*)(h_hi + (size_t)n0 * H_DIM + c8);
            bf16x8 v1 = *(const bf16x8*)(h_hi + (size_t)n1 * H_DIM + c8);
            bf16x8 v2 = *(const bf16x8*)(h_hi + (size_t)n2 * H_DIM + c8);
            bf16x8 v3 = *(const bf16x8*)(h_hi + (size_t)n3 * H_DIM + c8);
            #pragma unroll
            for (int j = 0; j < 8; ++j)
                a[j] += (bf2f((unsigned short)v0[j]) + bf2f((unsigned short)v1[j]))
                      + (bf2f((unsigned short)v2[j]) + bf2f((unsigned short)v3[j]));
        }
        if (i + 2 <= end) {
            int n0 = srcS[i], n1 = srcS[i + 1];
            bf16x8 v0 = *(const bf16x8*)(h_hi + (size_t)n0 * H_DIM + c8);
            bf16x8 v1 = *(const bf16x8*)(h_hi + (size_t)n1 * H_DIM + c8);
            #pragma unroll
            for (int j = 0; j < 8; ++j)
                a[j] += bf2f((unsigned short)v0[j]) + bf2f((unsigned short)v1[j]);
            i += 2;
        }
        if (i < end) {
            int n0 = srcS[i];
            bf16x8 v0 = *(const bf16x8*)(h_hi + (size_t)n0 * H_DIM + c8);
            #pragma unroll
            for (int j = 0; j < 8; ++j) a[j] += bf2f((unsigned short)v0[j]);
        }
    }
    bf16x8 o;
    #pragma unroll
    for (int j = 0; j < 8; ++j) o[j] = (short)f2bf(a[j]);
    *(bf16x8*)(sv + (size_t)node * H_DIM + c8) = o;   // node < N_PAD always
}

// ---------------- GRU step via MFMA ----------------
// Block = 8 waves = 32 rows x 128 ch; wave ct owns 32 rows x 16 ch (2 row-subtiles).
// Merged accumulators: r,z gates chain BOTH GEMMs into one C-tile each; n-gate split.
// Acc = 4 sets x 2 subtiles = 32 regs; working set ~100 combined -> fits the 128-reg
// budget of launch_bounds(512,4) WITHOUT spill (R12's 64-row variant needed ~144 and
// spilled: WRITE 280 MB). s A-frags direct from global; h staged in LDS (hold needed).
// LDS 17.4 KB; hnF epilogue reuse 16.9 KB. In-place h race-free per block.
__global__ __launch_bounds__(512, 4) void gru_kernel(
    const unsigned short* __restrict__ sv,
    unsigned short* __restrict__ h_hi, unsigned short* __restrict__ h_lo,
    const unsigned short* __restrict__ PBhi, const unsigned short* __restrict__ PBlo,
    int matI, const float* __restrict__ b_ih, const float* __restrict__ b_hh)
{
    __shared__ __align__(16) unsigned short buf[2 * 32 * SSTR];   // 17.4 KB
    unsigned short* sHh = buf;                  // h_hi tile (32 rows)
    unsigned short* sHl = buf + 32 * SSTR;      // h_lo tile
    float* hnF = (float*)buf;                   // epilogue reuse: 32*HSTR fp32 (16.9 KB)

    int nt = blockIdx.x;            // 3126
    int rowBase = nt * 32;
    int t = threadIdx.x;            // 512

    // phase 0: stage h tiles. 32 rows x 16 chunks of 8 ushorts = 512; 1 chunk/thread.
    {
        int row = t >> 4;
        int c8  = (t & 15) * 8;
        size_t g = (size_t)(rowBase + row) * H_DIM + c8;
        int l = row * SSTR + c8;
        *(bf16x8*)&sHh[l] = *(const bf16x8*)(h_hi + g);
        *(bf16x8*)&sHl[l] = *(const bf16x8*)(h_lo + g);
    }
    __syncthreads();

    int lane = t & 63;
    int ct   = t >> 6;              // wave id = channel tile 0..7
    int rloc = lane & 15;
    int kOff = (lane >> 4) * 8;

    f32x4 accRZ[2][2], accIn[2], accHn[2];   // merged r,z; split n  (32 regs)
    #pragma unroll
    for (int rs = 0; rs < 2; ++rs) {
        accRZ[0][rs] = (f32x4){0.f, 0.f, 0.f, 0.f};
        accRZ[1][rs] = (f32x4){0.f, 0.f, 0.f, 0.f};
        accIn[rs]    = (f32x4){0.f, 0.f, 0.f, 0.f};
        accHn[rs]    = (f32x4){0.f, 0.f, 0.f, 0.f};
    }

    const int fI0 = matI * 3;
    for (int kc = 0; kc < 4; ++kc) {
        int aOff = kc * 32 + kOff;
        // s A-frags: direct global, dense 64B lines (L1-shared across the 8 waves)
        bf16x8 aS[2];
        #pragma unroll
        for (int rs = 0; rs < 2; ++rs)
            aS[rs] = *(const bf16x8*)(sv + (size_t)(rowBase + rs * 16 + rloc) * H_DIM + aOff);
        // h A-frags from LDS
        bf16x8 aHh4[2], aHl4[2];
        #pragma unroll
        for (int rs = 0; rs < 2; ++rs) {
            int al = (rs * 16 + rloc) * SSTR + aOff;
            aHh4[rs] = *(const bf16x8*)(&sHh[al]);
            aHl4[rs] = *(const bf16x8*)(&sHl[al]);
        }
        #pragma unroll
        for (int g = 0; g < 3; ++g) {
            size_t oI = ((size_t)((fI0 + g) * 32 + ct * 4 + kc) * 64 + lane) * 8;
            size_t oH = ((size_t)((18  + g) * 32 + ct * 4 + kc) * 64 + lane) * 8;
            bf16x8 bIh = *(const bf16x8*)(PBhi + oI);
            bf16x8 bIl = *(const bf16x8*)(PBlo + oI);
            bf16x8 bHh = *(const bf16x8*)(PBhi + oH);
            bf16x8 bHl = *(const bf16x8*)(PBlo + oH);
            #pragma unroll
            for (int rs = 0; rs < 2; ++rs) {
                f32x4* tI = (g == 0) ? &accRZ[0][rs] : (g == 1) ? &accRZ[1][rs] : &accIn[rs];
                f32x4* tH = (g == 2) ? &accHn[rs] : tI;
                *tI = __builtin_amdgcn_mfma_f32_16x16x32_bf16(aS[rs],   bIh, *tI, 0, 0, 0);
                *tI = __builtin_amdgcn_mfma_f32_16x16x32_bf16(aS[rs],   bIl, *tI, 0, 0, 0);
                *tH = __builtin_amdgcn_mfma_f32_16x16x32_bf16(aHh4[rs], bHh, *tH, 0, 0, 0);
                *tH = __builtin_amdgcn_mfma_f32_16x16x32_bf16(aHl4[rs], bHh, *tH, 0, 0, 0);
                *tH = __builtin_amdgcn_mfma_f32_16x16x32_bf16(aHh4[rs], bHl, *tH, 0, 0, 0);
            }
        }
    }

    // ---- epilogue: thread-local GRU for all 8 values, then single LDS round-trip ----
    int c = ct * 16 + rloc;
    float br  = b_ih[c] + b_hh[c];               // merged r bias
    float bz  = b_ih[128 + c] + b_hh[128 + c];   // merged z bias
    float bin = b_ih[256 + c], bhn = b_hh[256 + c];
    int rl = (lane >> 4) * 4;       // local row base within each 16-row subtile

    float hnv[2][4];
    #pragma unroll
    for (int rs = 0; rs < 2; ++rs) {
        #pragma unroll
        for (int r = 0; r < 4; ++r) {
            int lrow = rs * 16 + rl + r;
            float hold = bf2f(sHh[lrow * SSTR + c]) + bf2f(sHl[lrow * SSTR + c]);
            float rr = 1.f / (1.f + __expf(-(accRZ[0][rs][r] + br)));
            float zz = 1.f / (1.f + __expf(-(accRZ[1][rs][r] + bz)));
            float pre = (accIn[rs][r] + bin) + rr * (accHn[rs][r] + bhn);
            float e2 = __expf(2.f * pre);
            float cand = 1.f - 2.f / (e2 + 1.f);  // tanh, overflow-safe
            hnv[rs][r] = (1.f - zz) * cand + zz * hold;
        }
    }
    __syncthreads();                // all hold reads done; tiles now reusable
    #pragma unroll
    for (int rs = 0; rs < 2; ++rs)
        #pragma unroll
        for (int r = 0; r < 4; ++r)
            hnF[(rs * 16 + rl + r) * HSTR + c] = hnv[rs][r];   // 2-way bank alias: free
    __syncthreads();                // hn tile complete
    // coop store: 32 rows x 32 float4 chunks = 1024, 512 threads x 2
    #pragma unroll
    for (int i = t; i < 32 * 32; i += 512) {
        int row = i >> 5;
        int c4  = (i & 31) * 4;
        int gRow = rowBase + row;
        if (gRow < N_NODES) {
            float4 v = *(const float4*)(&hnF[row * HSTR + c4]);
            ushort4 hh, ll;
            hh.x = f2bf(v.x); ll.x = f2bf(v.x - bf2f(hh.x));
            hh.y = f2bf(v.y); ll.y = f2bf(v.y - bf2f(hh.y));
            hh.z = f2bf(v.z); ll.z = f2bf(v.z - bf2f(hh.z));
            hh.w = f2bf(v.w); ll.w = f2bf(v.w - bf2f(hh.w));
            size_t o = (size_t)gRow * H_DIM + c4;
            *(ushort4*)(h_hi + o) = hh;
            *(ushort4*)(h_lo + o) = ll;
        }
    }
}

// ---------------- pool phase A: per-block segment partial sums + atomicAdd ----------------
__global__ void pool_partial(const unsigned short* __restrict__ h_hi,
                             const unsigned short* __restrict__ h_lo,
                             const int* __restrict__ batch,
                             float* __restrict__ pooled) {
    int b = blockIdx.x;             // 1563
    int t = threadIdx.x;            // 128
    int n0 = b * 64;
    if (n0 >= N_NODES) return;
    int nEnd = n0 + 64 < N_NODES ? n0 + 64 : N_NODES;
    int curG = batch[n0];
    float acc = 0.f;
    for (int n = n0; n < nEnd; ++n) {
        int g = batch[n];           // uniform across block
        if (g != curG) {            // uniform branch
            atomicAdd(&pooled[curG * H_DIM + t], acc);
            acc = 0.f;
            curG = g;
        }
        size_t o = (size_t)n * H_DIM + t;
        acc += bf2f(h_hi[o]) + bf2f(h_lo[o]);
    }
    atomicAdd(&pooled[curG * H_DIM + t], acc);
}

// ---------------- pool phase B: normalize + relu + prediction head ----------------
__global__ void pool_head(const float* __restrict__ pooled, const int* __restrict__ batch,
                          const float* __restrict__ w_pred, const float* __restrict__ b_pred,
                          float* __restrict__ out) {
    int g = blockIdx.x;             // 256 blocks
    int t = threadIdx.x;            // 128 threads
    __shared__ int bounds[2];
    __shared__ float red[2];
    if (t < 2) {
        int target = g + t;
        int lo = 0, hi = N_NODES;
        while (lo < hi) {
            int mid = (lo + hi) >> 1;
            if (batch[mid] < target) lo = mid + 1; else hi = mid;
        }
        bounds[t] = lo;
    }
    __syncthreads();
    int cnt = bounds[1] - bounds[0];
    float pv = pooled[g * H_DIM + t] / fmaxf((float)cnt, 1.f);
    pv = fmaxf(pv, 0.f);
    float v = pv * w_pred[t];
    #pragma unroll
    for (int off = 32; off > 0; off >>= 1) v += __shfl_down(v, off);
    if ((t & 63) == 0) red[t >> 6] = v;
    __syncthreads();
    if (t == 0) out[g] = red[0] + red[1] + b_pred[0];
}

extern "C" void kernel_launch(void* const* d_in, const int* in_sizes, int n_in,
                              void* d_out, int out_size, void* d_ws, size_t ws_size,
                              hipStream_t stream) {
    const float* x      = (const float*)d_in[0];
    const int*   ei     = (const int*)d_in[1];    // [2,E]: src = ei, dst = ei+E
    const int*   batch  = (const int*)d_in[2];
    const float* We     = (const float*)d_in[3];
    const float* Wm     = (const float*)d_in[4];
    const float* w_ih   = (const float*)d_in[5];
    const float* w_hh   = (const float*)d_in[6];  // [384][128] native col-major
    const float* b_ih   = (const float*)d_in[7];
    const float* b_hh   = (const float*)d_in[8];
    const float* w_pred = (const float*)d_in[9];
    const float* b_pred = (const float*)d_in[10];
    float* out = (float*)d_out;

    const size_t HN = (size_t)N_PAD * H_DIM;
    unsigned short* h_hi = (unsigned short*)d_ws;
    unsigned short* h_lo = h_hi + HN;
    unsigned short* sv   = h_lo + HN;                              // s, bf16 only
    float* M6 = (float*)(sv + HN);                                 // 6*384*128 fp32
    unsigned short* PBhi = (unsigned short*)(M6 + (size_t)STEPS * TH3 * H_DIM);
    unsigned short* PBlo = PBhi + 21 * 32 * 64 * 8;
    int* offs      = (int*)(PBlo + 21 * 32 * 64 * 8);              // N+1
    int* srcSorted = offs + (N_NODES + 1);                         // E
    float* pooled  = (float*)(srcSorted + N_EDGES);                // 256*128 fp32
    // CSR temporaries overlaid on sv (sv first written by gather, after CSR build)
    int* count     = (int*)sv;
    int* cursor    = count + N_NODES;
    int* blockSums = cursor + N_NODES;

    const int* esrc = ei;
    const int* edst = ei + N_EDGES;
    const int EB = (N_EDGES + 255) / 256;                // 6250
    const int NB = (N_NODES + 255) / 256;                // 391

    hipMemsetAsync(count, 0, 2 * (size_t)N_NODES * sizeof(int), stream);
    hipMemsetAsync(pooled, 0, (size_t)G_GRAPHS * H_DIM * sizeof(float), stream);
    hist_kernel<<<EB, 256, 0, stream>>>(edst, count);
    scan_block_kernel<<<NB, 256, 0, stream>>>(count, offs, blockSums);
    scan_sums_kernel<<<1, 512, 0, stream>>>(blockSums, NB);
    scan_add_kernel<<<NB, 256, 0, stream>>>(offs, blockSums);
    fill_kernel<<<EB, 256, 0, stream>>>(esrc, edst, offs, cursor, srcSorted);

    fuse_w_kernel<<<STEPS * TH3, H_DIM, 0, stream>>>(Wm, w_ih, M6);
    pack_kernel<<<21 * 32, 64, 0, stream>>>(M6, w_hh, PBhi, PBlo);
    embed_kernel<<<N_NODES / ET, H_DIM, 0, stream>>>(x, We, h_hi, h_lo);

    for (int i = 0; i < STEPS; ++i) {
        gather_kernel<<<(N_PAD * 16) / 256, 256, 0, stream>>>(h_hi, offs, srcSorted, sv);
        gru_kernel<<<N_PAD / 32, 512, 0, stream>>>(sv, h_hi, h_lo, PBhi, PBlo,
                                                   i, b_ih, b_hh);
    }

    pool_partial<<<(N_NODES + 63) / 64, H_DIM, 0, stream>>>(h_hi, h_lo, batch, pooled);
    pool_head<<<G_GRAPHS, H_DIM, 0, stream>>>(pooled, batch, w_pred, b_pred, out);
}